// Round 7
// baseline (74.652 us; speedup 1.0000x reference)
//
#include <hip/hip_runtime.h>
#include <stdint.h>

// Problem: B=32, P=16, E=50000, H=128
#define E_DIM 50000
#define EP2   50176          // padded to 56 * 896
#define HD    128
#define BD    32
#define PD    16
#define MD    512            // B*P
#define BM    32             // rows per gemm block
#define KCHUNK 896           // 14 stages of BK=64
#define NKC   56             // EP2 / KCHUNK exactly
#define NST   14
#define NEB   784            // embF blocks = EP2/64
#define ROWB  6272           // bits bytes per row (= EP2/8), 6250 real + 22 pad
#define EPSF  1e-5f

typedef short short8 __attribute__((ext_vector_type(8)));   // 8 bf16 (4 VGPRs)
typedef float f32x4  __attribute__((ext_vector_type(4)));

__device__ __forceinline__ uint16_t f2bf(float f) {
  uint32_t u = __float_as_uint(f);
  u += 0x7FFFu + ((u >> 16) & 1u);           // round-to-nearest-even
  return (uint16_t)(u >> 16);
}

// ---------------------------------------------------------------------------
// Kernel 1 (fused prep, both halves stream HBM concurrently):
//  blocks [0, 784): emb fp32 -> embF MFMA-fragment-packed bf16
//    region per block: 16 frags of 1KB: [w:4][fr:4][lane:64][8 bf16],
//    fr = kk*2+hfl, h=(2w+hfl)*16+(lane&15), e = bid*64 + kk*32 + (lane>>4)*8+j.
//    Row e=0 zeroed (padding_idx), e >= E_DIM zero-padded.
//  blocks [784, 1296): bit-pack inp row (bid-784): sequential row stream ->
//    bits[row][6272 bytes] (bit j of byte c = (inp[row][8c+j]==1)), bytes
//    6250..6271 zeroed; exact count -> cnt[row].
// ---------------------------------------------------------------------------
__global__ __launch_bounds__(256) void k_prep(const float* __restrict__ emb,
                                              const int* __restrict__ inp,
                                              uint16_t* __restrict__ embF,
                                              uint8_t* __restrict__ bits,
                                              float* __restrict__ cnt) {
  __shared__ __align__(16) uint16_t lds[HD * 64];
  __shared__ int sc[4];
  const int t = threadIdx.x;

  if (blockIdx.x < NEB) {
    // ---- embF repack ----
    const int e0 = blockIdx.x * 64;
#pragma unroll
    for (int pass = 0; pass < 8; ++pass) {
      const int el = pass * 8 + (t >> 5);
      const int h  = (t & 31) * 4;
      const int eg = e0 + el;
      float4 v = {0.f, 0.f, 0.f, 0.f};
      if (eg < E_DIM && eg != 0)
        v = *(const float4*)(emb + (size_t)eg * HD + h);
      const uint16_t q0 = f2bf(v.x), q1 = f2bf(v.y), q2 = f2bf(v.z), q3 = f2bf(v.w);
      lds[(h + 0) * 64 + (el ^ (((h + 0) & 7) << 3))] = q0;
      lds[(h + 1) * 64 + (el ^ (((h + 1) & 7) << 3))] = q1;
      lds[(h + 2) * 64 + (el ^ (((h + 2) & 7) << 3))] = q2;
      lds[(h + 3) * 64 + (el ^ (((h + 3) & 7) << 3))] = q3;
    }
    __syncthreads();
    const int w    = t >> 6;
    const int lane = t & 63;
    const int r16  = lane & 15;
    const int kgq  = (lane >> 4) * 8;
    uint16_t* outp = embF + (size_t)blockIdx.x * 8192 + (size_t)w * 2048 + lane * 8;
#pragma unroll
    for (int fr = 0; fr < 4; ++fr) {
      const int h  = (2 * w + (fr & 1)) * 16 + r16;
      const int el = (fr >> 1) * 32 + kgq;
      short8 d = *(const short8*)(lds + h * 64 + (el ^ ((h & 7) << 3)));
      *(short8*)(outp + fr * 512) = d;
    }
  } else {
    // ---- bit-pack one row ----
    const int r = blockIdx.x - NEB;
    const int* rp = inp + (size_t)r * E_DIM;
    uint8_t* bo = bits + (size_t)r * ROWB;
    int c = 0;
#pragma unroll 3
    for (int i = 0; i < 24; ++i) {
      const int idx = i * 2048 + t * 8;
      const int4 v0 = *(const int4*)(rp + idx);
      const int4 v1 = *(const int4*)(rp + idx + 4);
      const uint32_t b = (uint32_t)(v0.x == 1)        | ((uint32_t)(v0.y == 1) << 1)
                       | ((uint32_t)(v0.z == 1) << 2) | ((uint32_t)(v0.w == 1) << 3)
                       | ((uint32_t)(v1.x == 1) << 4) | ((uint32_t)(v1.y == 1) << 5)
                       | ((uint32_t)(v1.z == 1) << 6) | ((uint32_t)(v1.w == 1) << 7);
      c += __popc(b);
      bo[i * 256 + t] = (uint8_t)b;
    }
    // tail: ints 49152..49999 -> bytes 6144..6249; zero pad bytes 6250..6271
    if (t < 106) {
      const int idx = 49152 + t * 8;
      const int4 v0 = *(const int4*)(rp + idx);
      const int4 v1 = *(const int4*)(rp + idx + 4);
      const uint32_t b = (uint32_t)(v0.x == 1)        | ((uint32_t)(v0.y == 1) << 1)
                       | ((uint32_t)(v0.z == 1) << 2) | ((uint32_t)(v0.w == 1) << 3)
                       | ((uint32_t)(v1.x == 1) << 4) | ((uint32_t)(v1.y == 1) << 5)
                       | ((uint32_t)(v1.z == 1) << 6) | ((uint32_t)(v1.w == 1) << 7);
      c += __popc(b);
      bo[6144 + t] = (uint8_t)b;
    } else if (t < 128) {
      bo[6144 + t] = 0;
    }
    // exact count, block-local (deterministic, no atomics)
#pragma unroll
    for (int o = 1; o < 64; o <<= 1) c += __shfl_xor(c, o);
    if ((t & 63) == 0) sc[t >> 6] = c;
    __syncthreads();
    if (t == 0) cnt[r] = (float)(sc[0] + sc[1] + sc[2] + sc[3]);
  }
}

// ---------------------------------------------------------------------------
// Kernel 2: partial GEMM from L2. Zero LDS, zero barriers — waves free-run.
// A: 1-byte bit loads (L1-hot, 3.6 KB/block), unpacked to bf16 {0,1} frags.
// B: fragment-packed embF (L2-resident, 1 KB contiguous per wave-instr).
// 14 static phases, 1-phase register prefetch, bf16 partial output.
// Grid = 56 kc * 16 mb = 896 blocks.
// ---------------------------------------------------------------------------
__global__ __launch_bounds__(256, 4) void k_gemm(const uint8_t* __restrict__ bits,
                                                 const uint16_t* __restrict__ embF,
                                                 uint16_t* __restrict__ part) {
  const int t    = threadIdx.x;
  const int lane = t & 63;
  const int w    = t >> 6;

  // XCD-aware swizzle: 16 blocks sharing a kc land on one XCD (896 = 8*112).
  const int virt = (blockIdx.x & 7) * 112 + (blockIdx.x >> 3);
  const int mb = virt & 15;
  const int kc = virt >> 4;

  const int r16 = lane & 15;
  const int g   = lane >> 4;            // 0..3: k-byte within 4-byte group

  // A bit bases: byte (row, kc*112 + s*8 + kk*4 + g)
  const uint8_t* ab0 = bits + (size_t)(mb * BM + r16) * ROWB + kc * 112 + g;
  const uint8_t* ab1 = ab0 + 16 * ROWB;
  // B fragment base
  const uint16_t* bp = embF + (size_t)kc * (NST * 8192) + (size_t)w * 2048 + lane * 8;

  f32x4 acc00 = {0.f,0.f,0.f,0.f}, acc01 = {0.f,0.f,0.f,0.f};
  f32x4 acc10 = {0.f,0.f,0.f,0.f}, acc11 = {0.f,0.f,0.f,0.f};

  uint32_t aE0, aE1, aE2, aE3, aO0, aO1, aO2, aO3;
  short8 tE0, tE1, tE2, tE3, tO0, tO1, tO2, tO3;

  // byte b (8 mask bits) -> short8 of bf16 {0,1}
#define UNPACK(DST, B)                                            \
  {                                                               \
    union { uint32_t u[4]; short8 s; } x_;                        \
    x_.u[0] = ((B) & 1u) * 0x3F80u        + ((B) & 2u) * 0x1FC00000u;   \
    x_.u[1] = (((B) >> 2) & 1u) * 0x3F80u + (((B) >> 2) & 2u) * 0x1FC00000u; \
    x_.u[2] = (((B) >> 4) & 1u) * 0x3F80u + (((B) >> 4) & 2u) * 0x1FC00000u; \
    x_.u[3] = (((B) >> 6) & 1u) * 0x3F80u + (((B) >> 6) & 2u) * 0x1FC00000u; \
    DST = x_.s;                                                   \
  }

#define LOADA(A0, A1, A2, A3, S)                                  \
  A0 = ab0[(S) * 8];     A1 = ab0[(S) * 8 + 4];                   \
  A2 = ab1[(S) * 8];     A3 = ab1[(S) * 8 + 4];

#define LOADB(B0_, B1_, B2_, B3_, S)                              \
  B0_ = *(const short8*)(bp + (size_t)(S) * 8192);                \
  B1_ = *(const short8*)(bp + (size_t)(S) * 8192 + 512);          \
  B2_ = *(const short8*)(bp + (size_t)(S) * 8192 + 1024);         \
  B3_ = *(const short8*)(bp + (size_t)(S) * 8192 + 1536);

#define PHASE(A0, A1, A2, A3, B0_, B1_, B2_, B3_)                 \
  {                                                               \
    short8 f00, f01, f10, f11;                                    \
    UNPACK(f00, A0) UNPACK(f01, A1) UNPACK(f10, A2) UNPACK(f11, A3) \
    acc00 = __builtin_amdgcn_mfma_f32_16x16x32_bf16(f00, B0_, acc00, 0, 0, 0); \
    acc01 = __builtin_amdgcn_mfma_f32_16x16x32_bf16(f00, B1_, acc01, 0, 0, 0); \
    acc10 = __builtin_amdgcn_mfma_f32_16x16x32_bf16(f10, B0_, acc10, 0, 0, 0); \
    acc11 = __builtin_amdgcn_mfma_f32_16x16x32_bf16(f10, B1_, acc11, 0, 0, 0); \
    acc00 = __builtin_amdgcn_mfma_f32_16x16x32_bf16(f01, B2_, acc00, 0, 0, 0); \
    acc01 = __builtin_amdgcn_mfma_f32_16x16x32_bf16(f01, B3_, acc01, 0, 0, 0); \
    acc10 = __builtin_amdgcn_mfma_f32_16x16x32_bf16(f11, B2_, acc10, 0, 0, 0); \
    acc11 = __builtin_amdgcn_mfma_f32_16x16x32_bf16(f11, B3_, acc11, 0, 0, 0); \
  }

  LOADA(aE0, aE1, aE2, aE3, 0)
  LOADB(tE0, tE1, tE2, tE3, 0)
#pragma unroll
  for (int s = 0; s < NST; s += 2) {
    LOADA(aO0, aO1, aO2, aO3, s + 1)
    LOADB(tO0, tO1, tO2, tO3, s + 1)
    PHASE(aE0, aE1, aE2, aE3, tE0, tE1, tE2, tE3)
    if (s + 2 < NST) {
      LOADA(aE0, aE1, aE2, aE3, s + 2)
      LOADB(tE0, tE1, tE2, tE3, s + 2)
    }
    PHASE(aO0, aO1, aO2, aO3, tO0, tO1, tO2, tO3)
  }

#undef UNPACK
#undef LOADA
#undef LOADB
#undef PHASE

  // ---- epilogue: bf16 partial tile [kc][row][col] ----
  const int jr = (lane >> 4) << 2;
  uint16_t* pt = part + (size_t)kc * (MD * HD)
               + (size_t)(mb * BM + jr) * HD + w * 32 + r16;
#pragma unroll
  for (int j = 0; j < 4; ++j) {
    pt[j * HD]              = f2bf(acc00[j]);
    pt[j * HD + 16]         = f2bf(acc01[j]);
    pt[(16 + j) * HD]       = f2bf(acc10[j]);
    pt[(16 + j) * HD + 16]  = f2bf(acc11[j]);
  }
}

// ---------------------------------------------------------------------------
// Kernel 3: reduce bf16 partials over kc -> path_emb [512][128]
// 512 threads: 4-way kc split (14 each) + LDS combine; divide by exact count.
// ---------------------------------------------------------------------------
__global__ __launch_bounds__(512) void k_reduce(const uint16_t* __restrict__ part,
                                                const float* __restrict__ cnt,
                                                float* __restrict__ pe) {
  __shared__ float red[512];
  const int r   = blockIdx.x;
  const int t   = threadIdx.x;
  const int col = t & 127;
  const int sub = t >> 7;
  const uint16_t* pp = part + (size_t)(sub * 14) * (MD * HD) + (size_t)r * HD + col;
  float s = 0.f;
#pragma unroll
  for (int i = 0; i < 14; ++i)
    s += __uint_as_float((uint32_t)pp[(size_t)i * (MD * HD)] << 16);
  red[t] = s;
  __syncthreads();
  if (t < 128) {
    const float tot = red[t] + red[t + 128] + red[t + 256] + red[t + 384];
    const float c   = cnt[r];
    pe[r * HD + t] = (c > 0.f) ? (tot / c) : 0.f;
  }
}

// ---------------------------------------------------------------------------
// Kernel 4: mean over P, then LN -> FC1 -> ReLU -> BN -> LN -> FC2 -> ReLU -> BN
// ---------------------------------------------------------------------------
__global__ __launch_bounds__(128) void k_tail(
    const float* __restrict__ pe,
    const float* __restrict__ w1, const float* __restrict__ b1,
    const float* __restrict__ w2, const float* __restrict__ b2,
    const float* __restrict__ ln1g, const float* __restrict__ ln1b,
    const float* __restrict__ ln2g, const float* __restrict__ ln2b,
    const float* __restrict__ bn1g, const float* __restrict__ bn1b,
    const float* __restrict__ bn2g, const float* __restrict__ bn2b,
    float* __restrict__ out) {
  const int b = blockIdx.x, t = threadIdx.x;
  __shared__ float sh[HD];
  __shared__ float red[HD];

  float x = 0.f;
#pragma unroll
  for (int p = 0; p < PD; ++p) x += pe[(b * PD + p) * HD + t];
  x *= (1.f / PD);

  const float bninv = rsqrtf(1.f + EPSF);

  // ---- LN1 ----
  red[t] = x; __syncthreads();
  for (int o = 64; o > 0; o >>= 1) { if (t < o) red[t] += red[t + o]; __syncthreads(); }
  const float mu1 = red[0] * (1.f / HD); __syncthreads();
  const float d1 = x - mu1;
  red[t] = d1 * d1; __syncthreads();
  for (int o = 64; o > 0; o >>= 1) { if (t < o) red[t] += red[t + o]; __syncthreads(); }
  const float v1 = red[0] * (1.f / HD); __syncthreads();
  const float y1 = ln1g[t] * d1 * rsqrtf(v1 + EPSF) + ln1b[t];

  // ---- FC1 + ReLU + BN1 ----
  sh[t] = y1; __syncthreads();
  float a = b1[t];
  const float4* wrow1 = (const float4*)(w1 + (size_t)t * HD);
#pragma unroll 8
  for (int k = 0; k < 32; ++k) {
    const float4 w = wrow1[k];
    a += w.x * sh[k * 4] + w.y * sh[k * 4 + 1] + w.z * sh[k * 4 + 2] + w.w * sh[k * 4 + 3];
  }
  a = fmaxf(a, 0.f);
  a = bn1g[t] * a * bninv + bn1b[t];
  __syncthreads();

  // ---- LN2 ----
  red[t] = a; __syncthreads();
  for (int o = 64; o > 0; o >>= 1) { if (t < o) red[t] += red[t + o]; __syncthreads(); }
  const float mu2 = red[0] * (1.f / HD); __syncthreads();
  const float d2 = a - mu2;
  red[t] = d2 * d2; __syncthreads();
  for (int o = 64; o > 0; o >>= 1) { if (t < o) red[t] += red[t + o]; __syncthreads(); }
  const float v2 = red[0] * (1.f / HD); __syncthreads();
  const float y2 = ln2g[t] * d2 * rsqrtf(v2 + EPSF) + ln2b[t];

  // ---- FC2 + ReLU + BN2 ----
  sh[t] = y2; __syncthreads();
  float a2 = b2[t];
  const float4* wrow2 = (const float4*)(w2 + (size_t)t * HD);
#pragma unroll 8
  for (int k = 0; k < 32; ++k) {
    const float4 w = wrow2[k];
    a2 += w.x * sh[k * 4] + w.y * sh[k * 4 + 1] + w.z * sh[k * 4 + 2] + w.w * sh[k * 4 + 3];
  }
  a2 = fmaxf(a2, 0.f);
  a2 = bn2g[t] * a2 * bninv + bn2b[t];
  out[b * HD + t] = a2;
}

// ---------------------------------------------------------------------------
extern "C" void kernel_launch(void* const* d_in, const int* in_sizes, int n_in,
                              void* d_out, int out_size, void* d_ws, size_t ws_size,
                              hipStream_t stream) {
  const int*   inp  = (const int*)d_in[0];
  const float* emb  = (const float*)d_in[1];
  const float* w1   = (const float*)d_in[2];
  const float* b1   = (const float*)d_in[3];
  const float* w2   = (const float*)d_in[4];
  const float* b2   = (const float*)d_in[5];
  const float* ln1g = (const float*)d_in[6];
  const float* ln1b = (const float*)d_in[7];
  const float* ln2g = (const float*)d_in[8];
  const float* ln2b = (const float*)d_in[9];
  const float* bn1g = (const float*)d_in[10];
  const float* bn1b = (const float*)d_in[11];
  const float* bn2g = (const float*)d_in[12];
  const float* bn2b = (const float*)d_in[13];
  float* out = (float*)d_out;

  // workspace layout (23.66 MB total)
  char* ws = (char*)d_ws;
  uint8_t*  bits = (uint8_t*)ws;                            // 512*6272   = 3,211,264 B
  uint16_t* embF = (uint16_t*)(ws + 3211264);               // 784*8192*2 = 12,845,056 B
  uint16_t* part = (uint16_t*)(ws + 3211264 + 12845056);    // 56*512*128*2 = 7,340,032 B
  float*    cnt  = (float*)(ws + 3211264 + 12845056 + 7340032);        // 2,048 B
  float*    pe   = (float*)(ws + 3211264 + 12845056 + 7340032 + 2048); // 262,144 B

  k_prep<<<NEB + MD, 256, 0, stream>>>(emb, inp, embF, bits, cnt);
  k_gemm<<<NKC * 16, 256, 0, stream>>>(bits, embF, part);
  k_reduce<<<MD, 512, 0, stream>>>(part, cnt, pe);
  k_tail<<<BD, 128, 0, stream>>>(pe, w1, b1, w2, b2, ln1g, ln1b, ln2g, ln2b,
                                 bn1g, bn1b, bn2g, bn2b, out);
}

// Round 8
// 61.952 us; speedup vs baseline: 1.2050x; 1.2050x over previous
//
#include <hip/hip_runtime.h>
#include <stdint.h>

// Problem: B=32, P=16, E=50000, H=128
#define E_DIM 50000
#define EP2   50176          // padded: 112 * 448 = 784 * 64
#define HD    128
#define BD    32
#define PD    16
#define MD    512            // B*P
#define KCHUNK 448           // 7 stages of 64
#define NKC   112            // EP2 / KCHUNK exactly
#define NST   7
#define NEB   784            // embF 64-e stages = EP2/64
#define EPSF  1e-5f

typedef short short8 __attribute__((ext_vector_type(8)));   // 8 bf16 (4 VGPRs)
typedef float f32x4  __attribute__((ext_vector_type(4)));

__device__ __forceinline__ uint16_t f2bf(float f) {
  uint32_t u = __float_as_uint(f);
  u += 0x7FFFu + ((u >> 16) & 1u);           // round-to-nearest-even
  return (uint16_t)(u >> 16);
}

// ---------------------------------------------------------------------------
// Kernel 1 (fused prep):
//  blocks [0,784): emb fp32 -> embF fragment-packed bf16. Stage g covers
//    e0=g*64. Within the 16KB stage: 16 frags of 1KB, frag f: ks=f>>3,
//    c4=f&7; frag[lane][j]: h = c4*16 + (lane&15),
//    e = e0 + ks*32 + (lane>>4)*8 + j. Row e=0 zeroed, e>=E_DIM zero-padded.
//  blocks [784,1296): bit-pack inp row r=bid-784 into kc-major bitsT:
//    byte c0 (bits of e=8*c0..+7) -> bitsT[(c0/56)*28672 + r*56 + c0%56];
//    bytes for e>=50000 zeroed. Exact per-row count -> cnt[r].
// ---------------------------------------------------------------------------
__global__ __launch_bounds__(256) void k_prep(const float* __restrict__ emb,
                                              const int* __restrict__ inp,
                                              uint16_t* __restrict__ embF,
                                              uint8_t* __restrict__ bitsT,
                                              float* __restrict__ cnt) {
  __shared__ __align__(16) uint16_t lds[HD * 64];
  __shared__ int sc[4];
  const int t = threadIdx.x;

  if (blockIdx.x < NEB) {
    // ---- embF repack ----
    const int e0 = blockIdx.x * 64;
#pragma unroll
    for (int pass = 0; pass < 8; ++pass) {
      const int el = pass * 8 + (t >> 5);
      const int h  = (t & 31) * 4;
      const int eg = e0 + el;
      float4 v = {0.f, 0.f, 0.f, 0.f};
      if (eg < E_DIM && eg != 0)
        v = *(const float4*)(emb + (size_t)eg * HD + h);
      const uint16_t q0 = f2bf(v.x), q1 = f2bf(v.y), q2 = f2bf(v.z), q3 = f2bf(v.w);
      lds[(h + 0) * 64 + (el ^ (((h + 0) & 7) << 3))] = q0;
      lds[(h + 1) * 64 + (el ^ (((h + 1) & 7) << 3))] = q1;
      lds[(h + 2) * 64 + (el ^ (((h + 2) & 7) << 3))] = q2;
      lds[(h + 3) * 64 + (el ^ (((h + 3) & 7) << 3))] = q3;
    }
    __syncthreads();
    const int w    = t >> 6;
    const int lane = t & 63;
    const int r16  = lane & 15;
    const int kgq  = (lane >> 4) * 8;
    uint16_t* outp = embF + (size_t)blockIdx.x * 8192 + lane * 8;
#pragma unroll
    for (int fr = 0; fr < 4; ++fr) {
      const int f  = w * 4 + fr;               // 0..15: ks=f>>3, c4=f&7
      const int h  = (f & 7) * 16 + r16;
      const int el = (f >> 3) * 32 + kgq;
      // el % 8 == 0, XOR swizzle touches bits 3..5 only -> 16B stays contiguous
      short8 d = *(const short8*)(lds + h * 64 + (el ^ ((h & 7) << 3)));
      *(short8*)(outp + f * 512) = d;
    }
  } else {
    // ---- bit-pack one row into kc-major bitsT ----
    const int r = blockIdx.x - NEB;
    const int* rp = inp + (size_t)r * E_DIM;
    int c = 0;
#pragma unroll 3
    for (int i = 0; i < 24; ++i) {
      const int idx = i * 2048 + t * 8;
      const int4 v0 = *(const int4*)(rp + idx);
      const int4 v1 = *(const int4*)(rp + idx + 4);
      const uint32_t b = (uint32_t)(v0.x == 1)        | ((uint32_t)(v0.y == 1) << 1)
                       | ((uint32_t)(v0.z == 1) << 2) | ((uint32_t)(v0.w == 1) << 3)
                       | ((uint32_t)(v1.x == 1) << 4) | ((uint32_t)(v1.y == 1) << 5)
                       | ((uint32_t)(v1.z == 1) << 6) | ((uint32_t)(v1.w == 1) << 7);
      c += __popc(b);
      const int c0 = i * 256 + t;
      bitsT[(size_t)(c0 / 56) * 28672 + r * 56 + (c0 % 56)] = (uint8_t)b;
    }
    // tail: bytes 6144..6249 real, 6250..6271 zero
    if (t < 106) {
      const int idx = 49152 + t * 8;
      const int4 v0 = *(const int4*)(rp + idx);
      const int4 v1 = *(const int4*)(rp + idx + 4);
      const uint32_t b = (uint32_t)(v0.x == 1)        | ((uint32_t)(v0.y == 1) << 1)
                       | ((uint32_t)(v0.z == 1) << 2) | ((uint32_t)(v0.w == 1) << 3)
                       | ((uint32_t)(v1.x == 1) << 4) | ((uint32_t)(v1.y == 1) << 5)
                       | ((uint32_t)(v1.z == 1) << 6) | ((uint32_t)(v1.w == 1) << 7);
      c += __popc(b);
      const int c0 = 6144 + t;
      bitsT[(size_t)(c0 / 56) * 28672 + r * 56 + (c0 % 56)] = (uint8_t)b;
    } else if (t < 128) {
      const int c0 = 6144 + t;
      bitsT[(size_t)(c0 / 56) * 28672 + r * 56 + (c0 % 56)] = 0;
    }
#pragma unroll
    for (int o = 1; o < 64; o <<= 1) c += __shfl_xor(c, o);
    if ((t & 63) == 0) sc[t >> 6] = c;
    __syncthreads();
    if (t == 0) cnt[r] = (float)(sc[0] + sc[1] + sc[2] + sc[3]);
  }
}

// ---------------------------------------------------------------------------
// Kernel 2: partial GEMM, all-rows-per-block. Grid = 112 kc x 4 col-quarters
// = 448 blocks x 512 thr (8 waves). Stage B slice (28KB frag-packed) + A bits
// (28KB) into LDS once; then 7 unrolled phases of pure LDS->MFMA: no global
// loads, no barriers, no inter-block B reuse needed (B read once per block).
// B total = 4 x 12.8 MB = 51 MB (vs 205 MB in rounds 5-7).
// ---------------------------------------------------------------------------
__global__ __launch_bounds__(512, 4) void k_gemm(const uint8_t* __restrict__ bitsT,
                                                 const uint16_t* __restrict__ embF,
                                                 uint16_t* __restrict__ part) {
  __shared__ __align__(16) uint8_t lds[57344];   // [0,28672): B frags, [28672,..): A bits

  const int t    = threadIdx.x;
  const int lane = t & 63;
  const int w    = t >> 6;
  const int kc   = blockIdx.x >> 2;
  const int ch   = blockIdx.x & 3;               // col quarter: cols ch*32..+31

  // ---- stage: B 1792x16B + A 1792x16B, reg-staged, one barrier ----
  {
    const char* eb = (const char*)embF + (size_t)kc * 114688;
    const char* ab = (const char*)bitsT + (size_t)kc * 28672;
#define BADDR(IDX) (eb + ((IDX) >> 8) * 16384 + ((((IDX) >> 7) & 1) * 8192) \
                       + ((ch * 2 + (((IDX) >> 6) & 1)) * 1024) + ((IDX) & 63) * 16)
    uint4 b0, b1, b2, b3, a0, a1, a2, a3;
    b0 = *(const uint4*)BADDR(t);
    b1 = *(const uint4*)BADDR(512 + t);
    b2 = *(const uint4*)BADDR(1024 + t);
    a0 = *(const uint4*)(ab + t * 16);
    a1 = *(const uint4*)(ab + (512 + t) * 16);
    a2 = *(const uint4*)(ab + (1024 + t) * 16);
    if (t < 256) {
      b3 = *(const uint4*)BADDR(1536 + t);
      a3 = *(const uint4*)(ab + (1536 + t) * 16);
    }
    *(uint4*)(lds + t * 16)                  = b0;
    *(uint4*)(lds + (512 + t) * 16)          = b1;
    *(uint4*)(lds + (1024 + t) * 16)         = b2;
    *(uint4*)(lds + 28672 + t * 16)          = a0;
    *(uint4*)(lds + 28672 + (512 + t) * 16)  = a1;
    *(uint4*)(lds + 28672 + (1024 + t) * 16) = a2;
    if (t < 256) {
      *(uint4*)(lds + (1536 + t) * 16)          = b3;
      *(uint4*)(lds + 28672 + (1536 + t) * 16)  = a3;
    }
#undef BADDR
  }
  __syncthreads();

  const int r16 = lane & 15;
  const int g4  = lane >> 4;
  // A byte for (rg,ks,s): lds[abase + rg*896 + s*8 + ks*4]
  const int abase = 28672 + (w * 64 + r16) * 56 + g4;
  // B frag for (ks,cg,s): lds + s*4096 + ks*2048 + cg*1024 + lane*16
  const int bbase = lane * 16;

  f32x4 acc[4][2];
#pragma unroll
  for (int rg = 0; rg < 4; ++rg)
#pragma unroll
    for (int cg = 0; cg < 2; ++cg) acc[rg][cg] = (f32x4){0.f, 0.f, 0.f, 0.f};

  // r7-verified unpack: byte (8 mask bits) -> short8 of bf16 {0,1}
#define UNPACK(DST, B)                                            \
  {                                                               \
    union { uint32_t u[4]; short8 s; } x_;                        \
    x_.u[0] = ((B) & 1u) * 0x3F80u        + ((B) & 2u) * 0x1FC00000u;   \
    x_.u[1] = (((B) >> 2) & 1u) * 0x3F80u + (((B) >> 2) & 2u) * 0x1FC00000u; \
    x_.u[2] = (((B) >> 4) & 1u) * 0x3F80u + (((B) >> 4) & 2u) * 0x1FC00000u; \
    x_.u[3] = (((B) >> 6) & 1u) * 0x3F80u + (((B) >> 6) & 2u) * 0x1FC00000u; \
    DST = x_.s;                                                   \
  }

#pragma unroll
  for (int s = 0; s < NST; ++s) {
    short8 bf[2][2];
#pragma unroll
    for (int ks = 0; ks < 2; ++ks)
#pragma unroll
      for (int cg = 0; cg < 2; ++cg)
        bf[ks][cg] = *(const short8*)(lds + s * 4096 + ks * 2048 + cg * 1024 + bbase);
#pragma unroll
    for (int rg = 0; rg < 4; ++rg) {
#pragma unroll
      for (int ks = 0; ks < 2; ++ks) {
        const uint32_t b = lds[abase + rg * 896 + s * 8 + ks * 4];
        short8 af;
        UNPACK(af, b)
        acc[rg][0] = __builtin_amdgcn_mfma_f32_16x16x32_bf16(af, bf[ks][0], acc[rg][0], 0, 0, 0);
        acc[rg][1] = __builtin_amdgcn_mfma_f32_16x16x32_bf16(af, bf[ks][1], acc[rg][1], 0, 0, 0);
      }
    }
  }
#undef UNPACK

  // ---- epilogue: bf16 partial tile [kc][row][col] ----
  const int jr = (lane >> 4) << 2;                 // C/D: row=(l>>4)*4+j, col=l&15
#pragma unroll
  for (int rg = 0; rg < 4; ++rg)
#pragma unroll
    for (int cg = 0; cg < 2; ++cg) {
      uint16_t* pt = part + (size_t)kc * (MD * HD)
                   + (size_t)(w * 64 + rg * 16 + jr) * HD + ch * 32 + cg * 16 + r16;
#pragma unroll
      for (int j = 0; j < 4; ++j)
        pt[j * HD] = f2bf(acc[rg][cg][j]);
    }
}

// ---------------------------------------------------------------------------
// Kernel 3: reduce bf16 partials over 112 kc -> path_emb [512][128]
// ---------------------------------------------------------------------------
__global__ __launch_bounds__(512) void k_reduce(const uint16_t* __restrict__ part,
                                                const float* __restrict__ cnt,
                                                float* __restrict__ pe) {
  __shared__ float red[512];
  const int r   = blockIdx.x;
  const int t   = threadIdx.x;
  const int col = t & 127;
  const int sub = t >> 7;
  const uint16_t* pp = part + (size_t)(sub * 28) * (MD * HD) + (size_t)r * HD + col;
  float s = 0.f;
#pragma unroll
  for (int i = 0; i < 28; ++i)
    s += __uint_as_float((uint32_t)pp[(size_t)i * (MD * HD)] << 16);
  red[t] = s;
  __syncthreads();
  if (t < 128) {
    const float tot = red[t] + red[t + 128] + red[t + 256] + red[t + 384];
    const float c   = cnt[r];
    pe[r * HD + t] = (c > 0.f) ? (tot / c) : 0.f;
  }
}

// ---------------------------------------------------------------------------
// Kernel 4: mean over P, then LN -> FC1 -> ReLU -> BN -> LN -> FC2 -> ReLU -> BN
// ---------------------------------------------------------------------------
__global__ __launch_bounds__(128) void k_tail(
    const float* __restrict__ pe,
    const float* __restrict__ w1, const float* __restrict__ b1,
    const float* __restrict__ w2, const float* __restrict__ b2,
    const float* __restrict__ ln1g, const float* __restrict__ ln1b,
    const float* __restrict__ ln2g, const float* __restrict__ ln2b,
    const float* __restrict__ bn1g, const float* __restrict__ bn1b,
    const float* __restrict__ bn2g, const float* __restrict__ bn2b,
    float* __restrict__ out) {
  const int b = blockIdx.x, t = threadIdx.x;
  __shared__ float sh[HD];
  __shared__ float red[HD];

  float x = 0.f;
#pragma unroll
  for (int p = 0; p < PD; ++p) x += pe[(b * PD + p) * HD + t];
  x *= (1.f / PD);

  const float bninv = rsqrtf(1.f + EPSF);

  // ---- LN1 ----
  red[t] = x; __syncthreads();
  for (int o = 64; o > 0; o >>= 1) { if (t < o) red[t] += red[t + o]; __syncthreads(); }
  const float mu1 = red[0] * (1.f / HD); __syncthreads();
  const float d1 = x - mu1;
  red[t] = d1 * d1; __syncthreads();
  for (int o = 64; o > 0; o >>= 1) { if (t < o) red[t] += red[t + o]; __syncthreads(); }
  const float v1 = red[0] * (1.f / HD); __syncthreads();
  const float y1 = ln1g[t] * d1 * rsqrtf(v1 + EPSF) + ln1b[t];

  // ---- FC1 + ReLU + BN1 ----
  sh[t] = y1; __syncthreads();
  float a = b1[t];
  const float4* wrow1 = (const float4*)(w1 + (size_t)t * HD);
#pragma unroll 8
  for (int k = 0; k < 32; ++k) {
    const float4 w = wrow1[k];
    a += w.x * sh[k * 4] + w.y * sh[k * 4 + 1] + w.z * sh[k * 4 + 2] + w.w * sh[k * 4 + 3];
  }
  a = fmaxf(a, 0.f);
  a = bn1g[t] * a * bninv + bn1b[t];
  __syncthreads();

  // ---- LN2 ----
  red[t] = a; __syncthreads();
  for (int o = 64; o > 0; o >>= 1) { if (t < o) red[t] += red[t + o]; __syncthreads(); }
  const float mu2 = red[0] * (1.f / HD); __syncthreads();
  const float d2 = a - mu2;
  red[t] = d2 * d2; __syncthreads();
  for (int o = 64; o > 0; o >>= 1) { if (t < o) red[t] += red[t + o]; __syncthreads(); }
  const float v2 = red[0] * (1.f / HD); __syncthreads();
  const float y2 = ln2g[t] * d2 * rsqrtf(v2 + EPSF) + ln2b[t];

  // ---- FC2 + ReLU + BN2 ----
  sh[t] = y2; __syncthreads();
  float a2 = b2[t];
  const float4* wrow2 = (const float4*)(w2 + (size_t)t * HD);
#pragma unroll 8
  for (int k = 0; k < 32; ++k) {
    const float4 w = wrow2[k];
    a2 += w.x * sh[k * 4] + w.y * sh[k * 4 + 1] + w.z * sh[k * 4 + 2] + w.w * sh[k * 4 + 3];
  }
  a2 = fmaxf(a2, 0.f);
  a2 = bn2g[t] * a2 * bninv + bn2b[t];
  out[b * HD + t] = a2;
}

// ---------------------------------------------------------------------------
extern "C" void kernel_launch(void* const* d_in, const int* in_sizes, int n_in,
                              void* d_out, int out_size, void* d_ws, size_t ws_size,
                              hipStream_t stream) {
  const int*   inp  = (const int*)d_in[0];
  const float* emb  = (const float*)d_in[1];
  const float* w1   = (const float*)d_in[2];
  const float* b1   = (const float*)d_in[3];
  const float* w2   = (const float*)d_in[4];
  const float* b2   = (const float*)d_in[5];
  const float* ln1g = (const float*)d_in[6];
  const float* ln1b = (const float*)d_in[7];
  const float* ln2g = (const float*)d_in[8];
  const float* ln2b = (const float*)d_in[9];
  const float* bn1g = (const float*)d_in[10];
  const float* bn1b = (const float*)d_in[11];
  const float* bn2g = (const float*)d_in[12];
  const float* bn2b = (const float*)d_in[13];
  float* out = (float*)d_out;

  // workspace layout (31.0 MB total)
  char* ws = (char*)d_ws;
  uint8_t*  bitsT = (uint8_t*)ws;                          // 112*512*56 = 3,211,264 (+64 pad)
  uint16_t* embF  = (uint16_t*)(ws + 3211328);             // 784*16384  = 12,845,056
  uint16_t* part  = (uint16_t*)(ws + 3211328 + 12845056);  // 112*512*128*2 = 14,680,064
  float*    cnt   = (float*)(ws + 3211328 + 12845056 + 14680064);          // 2,048
  float*    pe    = (float*)(ws + 3211328 + 12845056 + 14680064 + 2048);   // 262,144

  k_prep<<<NEB + MD, 256, 0, stream>>>(emb, inp, embF, bitsT, cnt);
  k_gemm<<<NKC * 4, 512, 0, stream>>>(bitsT, embF, part);
  k_reduce<<<MD, 512, 0, stream>>>(part, cnt, pe);
  k_tail<<<BD, 128, 0, stream>>>(pe, w1, b1, w2, b2, ln1g, ln1b, ln2g, ln2b,
                                 bn1g, bn1b, bn2g, bn2b, out);
}